// Round 16
// baseline (291.159 us; speedup 1.0000x reference)
//
#include <hip/hip_runtime.h>

#define SS 1024
#define BB 128
#define HH 1024
#define LL 2
#define DD 2048
#define NROWS (SS*BB)            // 131072 (t,b) rows
#define TSEG 512                 // D=4 dispatches
#define NSEG 2
#define ROWSEG (TSEG*BB)         // 65536 rows per segment
#define RPW 8                    // rows per wave (ROWSEG / 8192)
#define NSCANB 8                 // scanner blocks: 1 wave x 16 batches (2 chains)
#define NWORKB 2048              // worker blocks (4 waves each -> 8192 waves)
#define L2E  1.4426950408889634f

typedef float f32x4 __attribute__((ext_vector_type(4)));

__device__ __forceinline__ float fast_rcp(float x)  { return __builtin_amdgcn_rcpf(x); }
__device__ __forceinline__ float exp2_(float x)     { return __builtin_amdgcn_exp2f(x); }

template<int CTRL>
__device__ __forceinline__ float qperm(float x){
    return __int_as_float(__builtin_amdgcn_update_dpp(0, __float_as_int(x), CTRL, 0xF, 0xF, true));
}
__device__ __forceinline__ float rowshr4(float x){
    return __int_as_float(__builtin_amdgcn_update_dpp(0, __float_as_int(x), 0x114, 0xF, 0xF, true));
}

// R27 = R24 + register-lean 2-chain ILP scan (R25's verified logic, fixed):
//  - NO launch_bounds cap: R25's lb(256,4) squeezed the SHARED allocation and
//    spilled both paths (its p0/p3 inflated too). Here the scan path (~80
//    VGPR: dwordx4 buf=32 + 2x state + hb) needs LESS than the worker path,
//    so kernel VGPR = workers' natural count -> worker BW unchanged BY
//    CONSTRUCTION; only scan behavior varies.
//  - pre relayout [b][gate][t]: t-contiguous per (b,gate) -> scan chunk =
//    8 x dwordx4 (was 32 scalar); k1 stores 4 lane-selected dwords per row
//    (same inst count as the old float4).
//  - #pragma unroll 1 on the chunk loop: body ~2.8KB (R25's fully-unrolled
//    ~90KB I$ blowup was a second unverified killer).
// Theory: per-step ~300cy is dependent-chain latency (setprio null, R22);
// 2 interleaved chains/lane overlap -> ~150cy/step effective -> S512 ~32us
// < 41us phase BW time -> scan hidden -> p1/p2 63 -> ~45us.
//   p0: k1(seg0)                    256 MB R
//   p1: k1(seg1) || scan(seg0)      256 MB R
//   p2: k3(seg0) || scan(seg1)      256 MB W
//   p3: k3(seg1) + finals           258 MB W
__global__ __launch_bounds__(256) void fused_phase(
    const float* __restrict__ x, const float* __restrict__ W,
    const float* __restrict__ bias, float* out,
    float* __restrict__ s_out, float* __restrict__ finals,
    float* __restrict__ sums, float* __restrict__ state,
    int s1, int s2, int s3, int fin)
{
    float* pre = out + (size_t)NROWS * HH;   // hT/cT rows (2 MB) as pre scratch;
                                             // overwritten only by phase-3 finals
    const int tid = threadIdx.x;

    if (blockIdx.x < NSCANB) {
        if (tid >= 64) return;
        const int lane = tid;

        if (s2 < 0) {
            // phase 0: compute 12 weight sums once (block 0 only)
            if (blockIdx.x == 0 && s1 == 0) {
                for (int s = 0; s < 12; ++s) {
                    const int base = (s < 4) ? s*DD
                                   : (s < 8) ? 4*DD + (s-4)*DD
                                             : 4*DD + (s-8)*DD + HH;
                    float v = 0.f;
                    #pragma unroll
                    for (int k = 0; k < 16; ++k) v += W[base + lane + k*64];
                    #pragma unroll
                    for (int off = 32; off >= 1; off >>= 1) v += __shfl_xor(v, off, 64);
                    if (lane == 0) sums[s] = v;
                }
            }
            return;
        }

        // ---------------- scan segment s2 (2 chains per lane) ----------------
        const int gate = lane & 3;
        const int L    = (lane >> 2) & 1;
        const int lb   = lane >> 3;
        const int sw   = blockIdx.x;             // 0..7

        const float sh = sums[L*4 + gate];       // sum W[L][g][0:H]
        const float sx = sums[8 + gate];         // sum W[1][g][H:2H]
        const float sc  = (gate == 1) ? (2.0f*L2E) : (-L2E);
        const float s_h = sh * sc;
        const float sxc = L ? sx * sc : 0.0f;
        const float pcc = L ? bias[4+gate] * sc : 0.0f;
        const float Ac  = (gate == 1) ? 1.0f : 0.0f;
        const float Bc  = (gate == 0) ? (2.0f*L2E) : ((gate == 1) ? -2.0f : 1.0f);

        const float* pb[2];
        float* so[2];
        #pragma unroll
        for (int c = 0; c < 2; ++c) {
            const int bb = sw*16 + c*8 + lb;
            pb[c] = pre + ((size_t)bb << 12) + (gate << 10);  // [b][gate][t]
            so[c] = s_out + (size_t)bb * SS;                  // [b][t]
        }

        const int t_lo = s2 * TSEG, t_hi = t_lo + TSEG;

        float h[2], cp[2], d1[2], d2[2], hb[2][4];
        #pragma unroll
        for (int c = 0; c < 2; ++c) {
            float4* st = (float4*)state + (sw*2 + c)*64 + lane;
            if (t_lo == 0) { h[c]=0.f; cp[c]=0.f; d1[c]=0.f; d2[c]=0.f; }
            else { float4 s = *st; h[c]=s.x; cp[c]=s.y; d1[c]=s.z; d2[c]=s.w; }
            hb[c][0]=0.f; hb[c][1]=0.f; hb[c][2]=0.f; hb[c][3]=0.f;
        }

        __builtin_amdgcn_s_setprio(3);

        f32x4 buf[2][4];
        #pragma unroll 1
        for (int ch = 0; ch < TSEG/16; ++ch) {
            const int tc = t_lo + ch*16;
            // chunk load: 8 dwordx4 (2 chains x 16 t-contiguous), one wait
            #pragma unroll
            for (int c = 0; c < 2; ++c)
                #pragma unroll
                for (int q = 0; q < 4; ++q)
                    buf[c][q] = *(const f32x4*)(pb[c] + tc + q*4);
            // 16 steps x 2 interleaved independent chains (pure VALU)
            #pragma unroll
            for (int uu = 0; uu < 16; ++uu) {
                #pragma unroll
                for (int c = 0; c < 2; ++c) {
                    const float p = L ? pcc : buf[c][uu>>2][uu&3];
                    const float P = fmaf(d2[c], sxc, p);     // L1 eats h0_{t-2}
                    const float g = fmaf(h[c], s_h, P);
                    const float v = fmaf(Bc, fast_rcp(1.0f + exp2_(g)), Ac);
                    const float w = v * qperm<0xB1>(v);
                    const float cpn = fmaf(qperm<0xAA>(v), cp[c], qperm<0x00>(w));
                    const float th = fmaf(-2.0f, fast_rcp(1.0f + exp2_(cpn)), 1.0f);
                    const float hn = qperm<0xFF>(v) * th;
                    // first 2 steps of segment: L1 redoes prev flush -> discard
                    const bool disc = (ch == 0) && (uu < 2) && L;
                    h[c]  = disc ? h[c]  : hn;
                    cp[c] = disc ? cp[c] : cpn;
                    d2[c] = d1[c];
                    d1[c] = rowshr4(h[c]);                   // L0 h -> L1 quad
                    hb[c][(uu+2)&3] = h[c];   // L1 h at global-u is h1[t+u-2]
                    // store 4 rows once slot 3 filled (gu%4==1, skip warm-up)
                    if (((uu&3)==1) && (ch > 0 || uu >= 5) && L && gate == 0)
                        *(float4*)(so[c] + tc + uu - 5)
                            = make_float4(hb[c][0],hb[c][1],hb[c][2],hb[c][3]);
                }
            }
        }

        float h0f[2], c0f[2];                    // L0 finals (flush skips L0)
        #pragma unroll
        for (int c = 0; c < 2; ++c) { h0f[c] = h[c]; c0f[c] = cp[c]; }

        // flush: 2 L1-only steps -> rows [t_hi-2, t_hi) into slots 2,3
        #pragma unroll
        for (int fs = 0; fs < 2; ++fs) {
            #pragma unroll
            for (int c = 0; c < 2; ++c) {
                const float p = pcc;             // L0 result discarded anyway
                const float P = fmaf(d2[c], sxc, p);
                const float g = fmaf(h[c], s_h, P);
                const float v = fmaf(Bc, fast_rcp(1.0f + exp2_(g)), Ac);
                const float w = v * qperm<0xB1>(v);
                const float cpn = fmaf(qperm<0xAA>(v), cp[c], qperm<0x00>(w));
                const float th = fmaf(-2.0f, fast_rcp(1.0f + exp2_(cpn)), 1.0f);
                const float hn = qperm<0xFF>(v) * th;
                if (L) { h[c] = hn; cp[c] = cpn;
                         if (fs == 0) hb[c][2] = hn; else hb[c][3] = hn; }
                d2[c] = d1[c];
            }
        }
        if (L && gate == 0) {
            #pragma unroll
            for (int c = 0; c < 2; ++c)
                *(float4*)(so[c] + t_hi - 4)
                    = make_float4(hb[c][0],hb[c][1],hb[c][2],hb[c][3]);
        }

        __builtin_amdgcn_s_setprio(0);

        #pragma unroll
        for (int c = 0; c < 2; ++c) {
            float4* st = (float4*)state + (sw*2 + c)*64 + lane;
            *st = make_float4(h[c], cp[c], d1[c], d2[c]);
        }

        if (t_hi == SS && gate == 0) {
            #pragma unroll
            for (int c = 0; c < 2; ++c) {
                const int bb = sw*16 + c*8 + lb;
                if (L) { finals[128+bb] = h[c];   finals[384+bb] = cp[c]  * (0.5f/L2E); }
                else   { finals[bb]     = h0f[c]; finals[256+bb] = c0f[c] * (0.5f/L2E); }
            }
        }
        return;
    }

    // ---------------- BW worker ----------------
    const int lane = tid & 63;
    const int gw   = (blockIdx.x - NSCANB)*4 + (tid >> 6);   // 0..8191

    if (s1 >= 0) {
        // k1: RPW consecutive rows per wave of segment s1 -> pre [b][gate][t].
        // x is read exactly once -> nontemporal (skip L2 allocate).
        float4 wv[4][4];
        #pragma unroll
        for (int j = 0; j < 4; ++j)
            #pragma unroll
            for (int it = 0; it < 4; ++it)
                wv[j][it] = *(const float4*)(W + j*DD + HH + it*256 + lane*4);
        const float4 b0 = *(const float4*)(bias);

        #pragma unroll 2
        for (int j = 0; j < RPW; ++j) {
            const int row = s1*ROWSEG + gw*RPW + j;
            const float* xr = x + (size_t)row * HH;
            float a0 = 0.f, a1 = 0.f, a2 = 0.f, a3 = 0.f;
            #pragma unroll
            for (int it = 0; it < 4; ++it) {
                f32x4 xv = __builtin_nontemporal_load((const f32x4*)xr + it*64 + lane);
                a0 = fmaf(xv.x, wv[0][it].x, fmaf(xv.y, wv[0][it].y, fmaf(xv.z, wv[0][it].z, fmaf(xv.w, wv[0][it].w, a0))));
                a1 = fmaf(xv.x, wv[1][it].x, fmaf(xv.y, wv[1][it].y, fmaf(xv.z, wv[1][it].z, fmaf(xv.w, wv[1][it].w, a1))));
                a2 = fmaf(xv.x, wv[2][it].x, fmaf(xv.y, wv[2][it].y, fmaf(xv.z, wv[2][it].z, fmaf(xv.w, wv[2][it].w, a2))));
                a3 = fmaf(xv.x, wv[3][it].x, fmaf(xv.y, wv[3][it].y, fmaf(xv.z, wv[3][it].z, fmaf(xv.w, wv[3][it].w, a3))));
            }
            #pragma unroll
            for (int off = 32; off >= 1; off >>= 1) {
                a0 += __shfl_xor(a0, off, 64);
                a1 += __shfl_xor(a1, off, 64);
                a2 += __shfl_xor(a2, off, 64);
                a3 += __shfl_xor(a3, off, 64);
            }
            // [b][gate][t] write: lanes 0..3 each store one scaled gate
            if (lane < 4) {
                const float g0 = (a0 + b0.x) * (-L2E);
                const float g1 = (a1 + b0.y) * ( 2.0f * L2E);
                const float g2 = (a2 + b0.z) * (-L2E);
                const float g3 = (a3 + b0.w) * (-L2E);
                const float mv = (lane==0) ? g0 : (lane==1) ? g1 : (lane==2) ? g2 : g3;
                const int b = row & (BB-1), t = row >> 7;
                pre[((size_t)b << 12) + (lane << 10) + t] = mv;
            }
        }
    }

    if (s3 >= 0) {
        // k3: 2 groups per wave; group = 4 consecutive t of one b (matches
        // transposed s_out[b][t] -> one broadcast float4 load per group).
        #pragma unroll
        for (int rep = 0; rep < 2; ++rep) {
            const int g  = gw*2 + rep;           // 0..16383
            const int b  = g >> 7;               // 0..127
            const int t0 = s3*TSEG + (g & 127)*4;
            float4 v4 = *(const float4*)(s_out + (size_t)b*SS + t0);
            #pragma unroll
            for (int jj = 0; jj < 4; ++jj) {
                const float vb = (jj==0) ? v4.x : (jj==1) ? v4.y : (jj==2) ? v4.z : v4.w;
                const f32x4 vv = {vb, vb, vb, vb};
                f32x4* dst = (f32x4*)(out + ((size_t)(t0+jj)*BB + b) * HH);
                #pragma unroll
                for (int it = 0; it < 4; ++it)
                    __builtin_nontemporal_store(vv, dst + it*64 + lane);
            }
        }
    }

    if (fin && gw < 512) {
        // finals: hT/cT rows (overwrites the pre region; scan is done)
        const float v = finals[gw];
        const f32x4 vv = {v, v, v, v};
        f32x4* dst = (f32x4*)(out + (size_t)(NROWS + gw) * HH);
        #pragma unroll
        for (int it = 0; it < 4; ++it)
            __builtin_nontemporal_store(vv, dst + it*64 + lane);
    }
}

extern "C" void kernel_launch(void* const* d_in, const int* in_sizes, int n_in,
                              void* d_out, int out_size, void* d_ws, size_t ws_size,
                              hipStream_t stream) {
    const float* x    = (const float*)d_in[0];   // [S,B,H]
    const float* W    = (const float*)d_in[1];   // [L,4,D]
    const float* bias = (const float*)d_in[2];   // [L,4]
    float* out = (float*)d_out;

    float* s_out  = (float*)d_ws;                // [131072] (transposed [b][t])
    float* finals = s_out + NROWS;               // [512]
    float* sums   = finals + 512;                // [16]
    float* state  = sums + 16;                   // [16*64*4] floats (16B aligned)

    // 4-phase pipeline: p0 k1(0); p1 k1(1)||scan(0); p2 k3(0)||scan(1);
    // p3 k3(1)+finals
    for (int p = 0; p < 4; ++p) {
        const int a1 = (p <= 1) ? p : -1;
        const int a2 = (p >= 1 && p <= 2) ? p - 1 : -1;
        const int a3 = (p >= 2) ? p - 2 : -1;
        const int fn = (p == 3) ? 1 : 0;
        hipLaunchKernelGGL(fused_phase, dim3(NSCANB + NWORKB), dim3(256), 0, stream,
                           x, W, bias, out, s_out, finals, sums, state,
                           a1, a2, a3, fn);
    }
}

// Round 17
// 234.044 us; speedup vs baseline: 1.2440x; 1.2440x over previous
//
#include <hip/hip_runtime.h>

#define SS 1024
#define BB 128
#define HH 1024
#define LL 2
#define DD 2048
#define NROWS (SS*BB)            // 131072 (t,b) rows
#define TSEG 512                 // D=4 dispatches
#define NSEG 2
#define ROWSEG (TSEG*BB)         // 65536 rows per segment
#define RPW 8                    // rows per wave (ROWSEG / 8192)
#define NSCANB 16                // scanner blocks (1 wave, 8 batches each)
#define NWORKB 2048              // worker blocks (4 waves each -> 8192 waves)
#define L2E  1.4426950408889634f

typedef float f32x4 __attribute__((ext_vector_type(4)));

__device__ __forceinline__ float fast_rcp(float x)  { return __builtin_amdgcn_rcpf(x); }
__device__ __forceinline__ float exp2_(float x)     { return __builtin_amdgcn_exp2f(x); }

template<int CTRL>
__device__ __forceinline__ float qperm(float x){
    return __int_as_float(__builtin_amdgcn_update_dpp(0, __float_as_int(x), CTRL, 0xF, 0xF, true));
}
__device__ __forceinline__ float rowshr4(float x){
    return __int_as_float(__builtin_amdgcn_update_dpp(0, __float_as_int(x), 0x114, 0xF, 0xF, true));
}

// R28 = final restoration of R24/R26 (3x reproduced: 233.7/234.9/234.4us).
// Structural floor, every term measured:
//   total ~= 41us (read seg0 before scan can start, BW-bound)
//          + 128us (serial LSTM chain: 1024 steps x ~300cy; p1+p2 measured
//            126us = exactly scan-paced; all middle BW work hides under it)
//          + 42us (write seg1 after scan ends, BW-bound)
//          + ~24us dispatch boundaries (3 x 8us, NSEG-fit R11/R13/R14)
// Refuted levers: batch-ILP scan (R23/R25/R27: batches are already parallel;
// ILP cannot shorten the serial t->t+1 chain -- R25/R27 regress identically
// under opposite register regimes); setprio (R22 null: not arbitration-
// bound); persistent dataflow (R15-R19: XCD coherence tax >= savings);
// 2-kernel split (R21: k3 at 2048 waves starves write BW); fewer/more
// dispatches (R13/R14: flat optimum at D=4).
//   p0: k1(seg0)                    256 MB R
//   p1: k1(seg1) || scan(seg0)      256 MB R
//   p2: k3(seg0) || scan(seg1)      256 MB W
//   p3: k3(seg1) + finals           258 MB W
__global__ __launch_bounds__(256) void fused_phase(
    const float* __restrict__ x, const float* __restrict__ W,
    const float* __restrict__ bias, float* out,
    float* __restrict__ s_out, float* __restrict__ finals,
    float* __restrict__ sums, float* __restrict__ state,
    int s1, int s2, int s3, int fin)
{
    float* pre = out + (size_t)NROWS * HH;   // hT/cT rows (2 MB) as pre scratch;
                                             // overwritten only by phase-3 finals
    const int tid = threadIdx.x;

    if (blockIdx.x < NSCANB) {
        if (tid >= 64) return;
        const int lane = tid;

        if (s2 < 0) {
            // phase 0: compute 12 weight sums once (block 0 only)
            if (blockIdx.x == 0 && s1 == 0) {
                for (int s = 0; s < 12; ++s) {
                    const int base = (s < 4) ? s*DD
                                   : (s < 8) ? 4*DD + (s-4)*DD
                                             : 4*DD + (s-8)*DD + HH;
                    float v = 0.f;
                    #pragma unroll
                    for (int k = 0; k < 16; ++k) v += W[base + lane + k*64];
                    #pragma unroll
                    for (int off = 32; off >= 1; off >>= 1) v += __shfl_xor(v, off, 64);
                    if (lane == 0) sums[s] = v;
                }
            }
            return;
        }

        // ---------------- scan segment s2 ----------------
        const int gate = lane & 3;
        const int L    = (lane >> 2) & 1;
        const int lb   = lane >> 3;
        const int bb   = blockIdx.x * 8 + lb;

        const float sh = sums[L*4 + gate];       // sum W[L][g][0:H]
        const float sx = sums[8 + gate];         // sum W[1][g][H:2H]
        const float sc  = (gate == 1) ? (2.0f*L2E) : (-L2E);
        const float s_h = sh * sc;
        const float sxc = L ? sx * sc : 0.0f;
        const float pcc = L ? bias[4+gate] * sc : 0.0f;
        const float Ac  = (gate == 1) ? 1.0f : 0.0f;
        const float Bc  = (gate == 0) ? (2.0f*L2E) : ((gate == 1) ? -2.0f : 1.0f);

        const float* pbase = pre + ((size_t)bb << 12) + gate;   // + t*4
        float* so = s_out + (size_t)bb * SS;                    // + t  (transposed)

        const int t_lo = s2 * TSEG, t_hi = t_lo + TSEG;

        float h, cp, h0d1, h0d2;                 // cp = 2*L2E*c
        float4* st = (float4*)state + blockIdx.x*64 + lane;
        if (t_lo == 0) { h = 0.f; cp = 0.f; h0d1 = 0.f; h0d2 = 0.f; }
        else { float4 s = *st; h = s.x; cp = s.y; h0d1 = s.z; h0d2 = s.w; }

        float hb0 = 0.f, hb1 = 0.f, hb2 = 0.f, hb3 = 0.f;  // h batch (slot = t&3)

        float buf[64];
        for (int ch = 0; ch < TSEG/64; ++ch) {
            const int tc = t_lo + ch*64;
            // chunk load: 64 scalars, one compiler wait before first use
            #pragma unroll
            for (int uu = 0; uu < 64; ++uu)
                buf[uu] = pbase[(size_t)(tc + uu) * 4];
            // 64 pure-VALU steps
            #pragma unroll
            for (int uu = 0; uu < 64; ++uu) {
                const float p = L ? pcc : buf[uu];
                const float P = fmaf(h0d2, sxc, p);      // L1 consumes h0_{t-2}
                const float g = fmaf(h, s_h, P);
                const float v = fmaf(Bc, fast_rcp(1.0f + exp2_(g)), Ac);
                const float w = v * qperm<0xB1>(v);
                const float cpn = fmaf(qperm<0xAA>(v), cp, qperm<0x00>(w));
                const float th = fmaf(-2.0f, fast_rcp(1.0f + exp2_(cpn)), 1.0f);
                const float hn = qperm<0xFF>(v) * th;
                // first 2 steps of segment: L1 redoes steps done by previous
                // segment's flush (or spin-up at t=0) -> discard.
                const bool disc = (ch == 0) && (uu < 2) && L;
                h  = disc ? h  : hn;
                cp = disc ? cp : cpn;
                h0d2 = h0d1;
                h0d1 = rowshr4(h);                       // L0 h -> L1 quad (DPP)

                // L1's h at global-u is h1[t_lo+u-2]; slot = (uu+2)&3
                if (((uu+2)&3)==0) hb0 = h;
                else if (((uu+2)&3)==1) hb1 = h;
                else if (((uu+2)&3)==2) hb2 = h;
                else hb3 = h;
                // store 4 rows once slot 3 filled (u%4==1, skip warm-up)
                if (((uu&3)==1) && (ch > 0 || uu >= 5) && L && gate == 0) {
                    *(float4*)(so + tc + uu - 5) = make_float4(hb0,hb1,hb2,hb3);
                }
            }
        }

        const float h0f = h, c0f = cp;           // L0 finals (flush skips L0)

        // flush: 2 L1-only steps -> rows [t_hi-2, t_hi) into slots 2,3
        #pragma unroll
        for (int fs = 0; fs < 2; ++fs) {
            const float p = L ? pcc : buf[63];   // L0 value unused this phase
            const float P = fmaf(h0d2, sxc, p);
            const float g = fmaf(h, s_h, P);
            const float v = fmaf(Bc, fast_rcp(1.0f + exp2_(g)), Ac);
            const float w = v * qperm<0xB1>(v);
            const float cpn = fmaf(qperm<0xAA>(v), cp, qperm<0x00>(w));
            const float th = fmaf(-2.0f, fast_rcp(1.0f + exp2_(cpn)), 1.0f);
            const float hn = qperm<0xFF>(v) * th;
            if (L) { h = hn; cp = cpn;
                     if (fs == 0) hb2 = hn; else hb3 = hn; }
            h0d2 = h0d1;
        }
        if (L && gate == 0)
            *(float4*)(so + t_hi - 4) = make_float4(hb0,hb1,hb2,hb3);

        *st = make_float4(h, cp, h0d1, h0d2);    // state for next segment

        if (t_hi == SS && gate == 0) {
            if (L) { finals[128+bb] = h;   finals[384+bb] = cp  * (0.5f/L2E); }
            else   { finals[bb]     = h0f; finals[256+bb] = c0f * (0.5f/L2E); }
        }
        return;
    }

    // ---------------- BW worker ----------------
    const int lane = tid & 63;
    const int gw   = (blockIdx.x - NSCANB)*4 + (tid >> 6);   // 0..8191

    if (s1 >= 0) {
        // k1: RPW consecutive rows per wave of segment s1 -> transposed pre.
        // x is read exactly once -> nontemporal (skip L2 allocate).
        float4 wv[4][4];
        #pragma unroll
        for (int j = 0; j < 4; ++j)
            #pragma unroll
            for (int it = 0; it < 4; ++it)
                wv[j][it] = *(const float4*)(W + j*DD + HH + it*256 + lane*4);
        const float4 b0 = *(const float4*)(bias);

        #pragma unroll 2
        for (int j = 0; j < RPW; ++j) {
            const int row = s1*ROWSEG + gw*RPW + j;
            const float* xr = x + (size_t)row * HH;
            float a0 = 0.f, a1 = 0.f, a2 = 0.f, a3 = 0.f;
            #pragma unroll
            for (int it = 0; it < 4; ++it) {
                f32x4 xv = __builtin_nontemporal_load((const f32x4*)xr + it*64 + lane);
                a0 = fmaf(xv.x, wv[0][it].x, fmaf(xv.y, wv[0][it].y, fmaf(xv.z, wv[0][it].z, fmaf(xv.w, wv[0][it].w, a0))));
                a1 = fmaf(xv.x, wv[1][it].x, fmaf(xv.y, wv[1][it].y, fmaf(xv.z, wv[1][it].z, fmaf(xv.w, wv[1][it].w, a1))));
                a2 = fmaf(xv.x, wv[2][it].x, fmaf(xv.y, wv[2][it].y, fmaf(xv.z, wv[2][it].z, fmaf(xv.w, wv[2][it].w, a2))));
                a3 = fmaf(xv.x, wv[3][it].x, fmaf(xv.y, wv[3][it].y, fmaf(xv.z, wv[3][it].z, fmaf(xv.w, wv[3][it].w, a3))));
            }
            #pragma unroll
            for (int off = 32; off >= 1; off >>= 1) {
                a0 += __shfl_xor(a0, off, 64);
                a1 += __shfl_xor(a1, off, 64);
                a2 += __shfl_xor(a2, off, 64);
                a3 += __shfl_xor(a3, off, 64);
            }
            if (lane == 0) {
                float4 r = make_float4((a0 + b0.x) * (-L2E),
                                       (a1 + b0.y) * ( 2.0f * L2E),
                                       (a2 + b0.z) * (-L2E),
                                       (a3 + b0.w) * (-L2E));
                const int b = row & (BB-1), t = row >> 7;
                *(float4*)(pre + (((size_t)b << 10) + t) * 4) = r;
            }
        }
    }

    if (s3 >= 0) {
        // k3: 2 groups per wave; group = 4 consecutive t of one b (matches
        // transposed s_out[b][t] -> one broadcast float4 load per group).
        #pragma unroll
        for (int rep = 0; rep < 2; ++rep) {
            const int g  = gw*2 + rep;           // 0..16383
            const int b  = g >> 7;               // 0..127
            const int t0 = s3*TSEG + (g & 127)*4;
            float4 v4 = *(const float4*)(s_out + (size_t)b*SS + t0);
            #pragma unroll
            for (int jj = 0; jj < 4; ++jj) {
                const float vb = (jj==0) ? v4.x : (jj==1) ? v4.y : (jj==2) ? v4.z : v4.w;
                const f32x4 vv = {vb, vb, vb, vb};
                f32x4* dst = (f32x4*)(out + ((size_t)(t0+jj)*BB + b) * HH);
                #pragma unroll
                for (int it = 0; it < 4; ++it)
                    __builtin_nontemporal_store(vv, dst + it*64 + lane);
            }
        }
    }

    if (fin && gw < 512) {
        // finals: hT/cT rows (overwrites the pre region; scan is done)
        const float v = finals[gw];
        const f32x4 vv = {v, v, v, v};
        f32x4* dst = (f32x4*)(out + (size_t)(NROWS + gw) * HH);
        #pragma unroll
        for (int it = 0; it < 4; ++it)
            __builtin_nontemporal_store(vv, dst + it*64 + lane);
    }
}

extern "C" void kernel_launch(void* const* d_in, const int* in_sizes, int n_in,
                              void* d_out, int out_size, void* d_ws, size_t ws_size,
                              hipStream_t stream) {
    const float* x    = (const float*)d_in[0];   // [S,B,H]
    const float* W    = (const float*)d_in[1];   // [L,4,D]
    const float* bias = (const float*)d_in[2];   // [L,4]
    float* out = (float*)d_out;

    float* s_out  = (float*)d_ws;                // [131072] (transposed [b][t])
    float* finals = s_out + NROWS;               // [512]
    float* sums   = finals + 512;                // [16]
    float* state  = sums + 16;                   // [16*64*4] floats (16B aligned)

    // 4-phase pipeline: p0 k1(0); p1 k1(1)||scan(0); p2 k3(0)||scan(1);
    // p3 k3(1)+finals
    for (int p = 0; p < 4; ++p) {
        const int a1 = (p <= 1) ? p : -1;
        const int a2 = (p >= 1 && p <= 2) ? p - 1 : -1;
        const int a3 = (p >= 2) ? p - 2 : -1;
        const int fn = (p == 3) ? 1 : 0;
        hipLaunchKernelGGL(fused_phase, dim3(NSCANB + NWORKB), dim3(256), 0, stream,
                           x, W, bias, out, s_out, finals, sums, state,
                           a1, a2, a3, fn);
    }
}